// Round 11
// baseline (198.460 us; speedup 1.0000x reference)
//
#include <hip/hip_runtime.h>

// out = B @ (X @ W):
//   wtrans: Wt_bf16[n][k] = bf16(W[k][n])
//   hist/scan/fill: CSR build
//   proj3:  x_proj_bf16 = bf16(X @ W). B (W-slice) in REGISTERS (32 frags =
//           128 VGPR, loaded once); X staged to LDS via global_load_lds
//           (deep vmcnt queue -> HBM-BW-bound), double-buffered 2-phase;
//           linear LDS dest + inverse-swizzled global src + swizzled ds_read.
//           Block 512thr = 2 groups x 4 waves; group shares a 16-row A-tile,
//           wave owns 64 output cols. Lane-permuted packed xp stores.
//   gather: wave per out row, batched independent 512B bf16-row gathers,
//           fp32 accumulate, direct fp32 out writes (unpermuting)

typedef short bf16x8 __attribute__((ext_vector_type(8)));
typedef float f32x4  __attribute__((ext_vector_type(4)));

#define PGRID 256

static __device__ __forceinline__ unsigned short f2bf(float f) {
    union { float f; unsigned u; } a; a.f = f;
    unsigned r = a.u + 0x7FFFu + ((a.u >> 16) & 1u);   // RNE
    return (unsigned short)(r >> 16);
}

static __device__ __forceinline__ float bf2f(unsigned short h) {
    union { unsigned u; float f; } a; a.u = (unsigned)h << 16;
    return a.f;
}

static __device__ __forceinline__ unsigned pack2(float f0, float f1) {
    return (unsigned)f2bf(f0) | ((unsigned)f2bf(f1) << 16);
}

static __device__ __forceinline__ bf16x8 cvt8(float4 lo, float4 hi) {
    union { bf16x8 v; unsigned u[4]; } r;
    r.u[0] = pack2(lo.x, lo.y);
    r.u[1] = pack2(lo.z, lo.w);
    r.u[2] = pack2(hi.x, hi.y);
    r.u[3] = pack2(hi.z, hi.w);
    return r.v;
}

static __device__ __forceinline__ void gload_lds16(const void* g, void* l) {
    __builtin_amdgcn_global_load_lds(
        (const __attribute__((address_space(1))) unsigned int*)g,
        (__attribute__((address_space(3))) unsigned int*)l,
        16, 0, 0);
}

__global__ __launch_bounds__(256) void wtrans_kernel(
    const float* __restrict__ W, unsigned short* __restrict__ Wt)
{
    int k = blockIdx.x;
    int n = threadIdx.x;
    Wt[(size_t)n * 256 + k] = f2bf(W[(size_t)k * 256 + n]);
}

__global__ __launch_bounds__(256) void hist_kernel(
    const int* __restrict__ b_rows, int* __restrict__ cnt, int nnz)
{
    int i = blockIdx.x * 256 + threadIdx.x;
    if (i < nnz) atomicAdd(&cnt[b_rows[i]], 1);
}

__global__ __launch_bounds__(1024) void scan_part_kernel(
    const int* __restrict__ cnt, int* __restrict__ partials, int M)
{
    int tid = threadIdx.x;
    int base = blockIdx.x * 4096;
    int s = 0;
    #pragma unroll
    for (int k = 0; k < 4; ++k) {
        int i = base + k * 1024 + tid;
        if (i < M) s += cnt[i];
    }
    #pragma unroll
    for (int d = 1; d < 64; d <<= 1) s += __shfl_xor(s, d);
    __shared__ int wsum[16];
    int lane = tid & 63, wid = tid >> 6;
    if (lane == 0) wsum[wid] = s;
    __syncthreads();
    if (tid == 0) {
        int t = 0;
        #pragma unroll
        for (int w = 0; w < 16; ++w) t += wsum[w];
        partials[blockIdx.x] = t;
    }
}

__global__ __launch_bounds__(64) void scan_mid_kernel(
    int* __restrict__ partials, int* __restrict__ off, int np, int M)
{
    int lane = threadIdx.x;
    int v = (lane < np) ? partials[lane] : 0;
    int x = v;
    #pragma unroll
    for (int d = 1; d < 64; d <<= 1) { int y = __shfl_up(x, d); if (lane >= d) x += y; }
    if (lane < np) partials[lane] = x - v;
    if (lane == 63) off[M] = x;
}

__global__ __launch_bounds__(1024) void scan_apply_kernel(
    const int* __restrict__ cnt, const int* __restrict__ partials,
    int* __restrict__ off, int* __restrict__ cursor, int M)
{
    int tid = threadIdx.x;
    int base = blockIdx.x * 4096 + tid * 4;
    int4 v = make_int4(0, 0, 0, 0);
    if (base + 3 < M) v = *reinterpret_cast<const int4*>(cnt + base);
    else {
        if (base + 0 < M) v.x = cnt[base + 0];
        if (base + 1 < M) v.y = cnt[base + 1];
        if (base + 2 < M) v.z = cnt[base + 2];
    }
    int s1 = v.x + v.y, s2 = s1 + v.z, tsum = s2 + v.w;
    int x = tsum;
    int lane = tid & 63, wid = tid >> 6;
    #pragma unroll
    for (int d = 1; d < 64; d <<= 1) { int y = __shfl_up(x, d); if (lane >= d) x += y; }
    __shared__ int wsum[16];
    if (lane == 63) wsum[wid] = x;
    __syncthreads();
    if (wid == 0 && lane < 16) {
        int w = wsum[lane];
        int xx = w;
        #pragma unroll
        for (int d = 1; d < 16; d <<= 1) { int y = __shfl_up(xx, d); if (lane >= d) xx += y; }
        wsum[lane] = xx - w;
    }
    __syncthreads();
    int excl = (x - tsum) + wsum[wid] + partials[blockIdx.x];
    int o0 = excl, o1 = excl + v.x, o2 = excl + s1, o3 = excl + s2;
    if (base + 0 < M) { off[base + 0] = o0; cursor[base + 0] = o0; }
    if (base + 1 < M) { off[base + 1] = o1; cursor[base + 1] = o1; }
    if (base + 2 < M) { off[base + 2] = o2; cursor[base + 2] = o2; }
    if (base + 3 < M) { off[base + 3] = o3; cursor[base + 3] = o3; }
}

__global__ __launch_bounds__(256) void fill_kernel(
    const float* __restrict__ b_vals, const int* __restrict__ b_rows,
    const int* __restrict__ b_cols, int* __restrict__ cursor,
    int* __restrict__ csr_col, float* __restrict__ csr_val, int nnz)
{
    int i = blockIdx.x * 256 + threadIdx.x;
    if (i < nnz) {
        int r = b_rows[i];
        int pos = atomicAdd(&cursor[r], 1);
        csr_col[pos] = b_cols[i];
        csr_val[pos] = b_vals[i];
    }
}

// x_proj = bf16(X @ W); W-slice in registers, X staged via global_load_lds.
// Block = 512 thr = 2 groups x 4 waves. Group g handles tile = blk*2+g + r*512
// (16 rows). Wave ww (0..3) in group owns cols [ww*64, ww*64+64).
// LDS A-tile layout (per rule #21): physical byte (row*1024 + L*16) holds
// logical fp32 k-offset ((L*16) ^ ((row&7)<<4)); ds_read applies same XOR.
// xp contract (shared with gather): row halfword [g*64+a*4+t] = ch {64g+a+16t}.
__global__ __launch_bounds__(512, 2) void proj3_kernel(
    const float* __restrict__ X, const unsigned short* __restrict__ Wt,
    unsigned short* __restrict__ xp, int ntiles)
{
    __shared__ __align__(16) unsigned char abuf[2][2][16 * 1024];  // 64 KB

    int tid = threadIdx.x;
    int lane = tid & 63, w = tid >> 6;       // w 0..7
    int grp = w >> 2;                         // 0,1
    int ww  = w & 3;                          // col-slice index
    int arow = lane & 15;
    int kg = lane >> 4;                       // 0..3

    // ---- one-time B load into registers: b[nt][s], 128 VGPR
    bf16x8 b[4][8];
    {
        const char* wt = reinterpret_cast<const char*>(Wt);
        size_t nb = (size_t)(ww * 64 + arow) * 512 + kg * 16;
        #pragma unroll
        for (int nt = 0; nt < 4; ++nt)
            #pragma unroll
            for (int s = 0; s < 8; ++s)
                b[nt][s] = *reinterpret_cast<const bf16x8*>(
                    wt + nb + (size_t)nt * 16 * 512 + s * 64);
    }

    const char* Xb = reinterpret_cast<const char*>(X);
    int gid = blockIdx.x * 2 + grp;
    const int stride = PGRID * 2;            // 512 groups
    int rounds = (ntiles + stride - 1) / stride;

    int swz = (lane * 16);                   // lane's linear 16B slot in a row

    // prologue: stage round 0 into parity 0
    {
        int tile = gid;
        if (tile < ntiles) {
            #pragma unroll
            for (int ii = 0; ii < 4; ++ii) {
                int i = ww * 4 + ii;         // row of tile staged by this wave
                const void* src = Xb + (size_t)(tile * 16 + i) * 1024
                                     + (swz ^ ((i & 7) << 4));
                gload_lds16(src, &abuf[0][grp][i * 1024]);
            }
        }
    }
    __syncthreads();

    for (int r = 0; r < rounds; ++r) {
        int tile = gid + r * stride;
        int p = r & 1;

        // issue next round's stage first (overlaps this round's compute)
        {
            int ntile = gid + (r + 1) * stride;
            if (ntile < ntiles) {
                #pragma unroll
                for (int ii = 0; ii < 4; ++ii) {
                    int i = ww * 4 + ii;
                    const void* src = Xb + (size_t)(ntile * 16 + i) * 1024
                                         + (swz ^ ((i & 7) << 4));
                    gload_lds16(src, &abuf[p ^ 1][grp][i * 1024]);
                }
            }
        }

        if (tile < ntiles) {
            const unsigned char* ab = abuf[p][grp];
            int rx = arow * 1024;
            int xo = (arow & 7) << 4;
            f32x4 acc[4] = {};
            #pragma unroll
            for (int s = 0; s < 8; ++s) {
                int base = kg * 32 + s * 128;
                float4 lo = *reinterpret_cast<const float4*>(ab + rx + ((base +  0) ^ xo));
                float4 hi = *reinterpret_cast<const float4*>(ab + rx + ((base + 16) ^ xo));
                bf16x8 a = cvt8(lo, hi);
                #pragma unroll
                for (int nt = 0; nt < 4; ++nt)
                    acc[nt] = __builtin_amdgcn_mfma_f32_16x16x32_bf16(a, b[nt][s], acc[nt], 0, 0, 0);
            }
            // epilogue: lane stores rows tile*16 + kg*4 + rr, col-slice ww
            int R = tile * 16;
            #pragma unroll
            for (int rr = 0; rr < 4; ++rr) {
                int row = R + kg * 4 + rr;
                ushort4 h;
                h.x = f2bf(acc[0][rr]);
                h.y = f2bf(acc[1][rr]);
                h.z = f2bf(acc[2][rr]);
                h.w = f2bf(acc[3][rr]);
                *reinterpret_cast<ushort4*>(xp + (size_t)row * 256 + ww * 64 + arow * 4) = h;
            }
        }
        __syncthreads();   // drains vmcnt -> next round's buffer is ready
    }
}

// wave per out row; batched independent bf16-row gathers; fp32 out (unpermute).
__global__ __launch_bounds__(256) void gather_kernel(
    const unsigned short* __restrict__ xp, const float* __restrict__ csr_val,
    const int* __restrict__ csr_col, const int* __restrict__ off,
    float* __restrict__ out, int M)
{
    int row = blockIdx.x * 4 + (threadIdx.x >> 6);
    if (row >= M) return;
    int lane = threadIdx.x & 63;

    int s = off[row], e = off[row + 1];
    float a0 = 0.f, a1 = 0.f, a2 = 0.f, a3 = 0.f;

    for (int j = s; j < e; j += 8) {
        int nb = e - j;                         // wave-uniform
        int c[8]; float v[8]; ushort4 xs[8];
        #pragma unroll
        for (int t = 0; t < 8; ++t)
            if (t < nb) { c[t] = csr_col[j + t]; v[t] = csr_val[j + t]; }
        #pragma unroll
        for (int t = 0; t < 8; ++t)
            if (t < nb)
                xs[t] = *reinterpret_cast<const ushort4*>(
                    xp + (size_t)c[t] * 256 + lane * 4);   // 8B/lane, independent
        #pragma unroll
        for (int t = 0; t < 8; ++t)
            if (t < nb) {
                a0 += v[t] * bf2f(xs[t].x);
                a1 += v[t] * bf2f(xs[t].y);
                a2 += v[t] * bf2f(xs[t].z);
                a3 += v[t] * bf2f(xs[t].w);
            }
    }

    // lane holds true channels {64*(lane>>4) + (lane&15) + 16*t}
    int col0 = (lane >> 4) * 64 + (lane & 15);
    float* o = out + (size_t)row * 256;
    o[col0 +  0] = a0;
    o[col0 + 16] = a1;
    o[col0 + 32] = a2;
    o[col0 + 48] = a3;
}

extern "C" void kernel_launch(void* const* d_in, const int* in_sizes, int n_in,
                              void* d_out, int out_size, void* d_ws, size_t ws_size,
                              hipStream_t stream) {
    const float* x_src  = (const float*)d_in[0];
    const float* W      = (const float*)d_in[1];
    const float* b_vals = (const float*)d_in[2];
    const int*   b_rows = (const int*)d_in[3];
    const int*   b_cols = (const int*)d_in[4];

    const int C = 256;
    const int M = out_size / C;
    const int nnz = in_sizes[2];
    const int N = in_sizes[0] / C;

    char* ws = (char*)d_ws;
    unsigned short* Wt = (unsigned short*)ws;           ws += 256 * 256 * 2;
    int*   cnt     = (int*)ws;                          ws += (size_t)M * 4;
    int*   off     = (int*)ws;                          ws += (size_t)(M + 1) * 4;
    int*   cursor  = (int*)ws;                          ws += (size_t)M * 4;
    int*   partials= (int*)ws;                          ws += 64 * 4;
    int*   csr_col = (int*)ws;                          ws += (size_t)nnz * 4;
    float* csr_val = (float*)ws;                        ws += (size_t)nnz * 4;
    ws = (char*)(((size_t)ws + 63) & ~(size_t)63);
    unsigned short* xp = (unsigned short*)ws;           // N*512 bytes (~102 MB)

    float* out = (float*)d_out;

    hipMemsetAsync(cnt, 0, (size_t)M * 4, stream);

    wtrans_kernel<<<256, 256, 0, stream>>>(W, Wt);

    int nblk_nnz = (nnz + 255) / 256;
    hist_kernel<<<nblk_nnz, 256, 0, stream>>>(b_rows, cnt, nnz);

    int nb = (M + 4095) / 4096;
    scan_part_kernel<<<nb, 1024, 0, stream>>>(cnt, partials, M);
    scan_mid_kernel<<<1, 64, 0, stream>>>(partials, off, nb, M);
    scan_apply_kernel<<<nb, 1024, 0, stream>>>(cnt, partials, off, cursor, M);

    fill_kernel<<<nblk_nnz, 256, 0, stream>>>(b_vals, b_rows, b_cols, cursor,
                                              csr_col, csr_val, nnz);

    int ntiles = N / 16;                       // N=200000 -> 12500
    proj3_kernel<<<PGRID, 512, 0, stream>>>(x_src, Wt, xp, ntiles);

    gather_kernel<<<(M + 3) / 4, 256, 0, stream>>>(xp, csr_val, csr_col, off, out, M);
}